// Round 1
// baseline (295.629 us; speedup 1.0000x reference)
//
#include <hip/hip_runtime.h>
#include <math.h>

// Problem constants (from setup_inputs): B=8, D=512, Dh=64, T=8192, chunksize=16
#define BB 8
#define DD 512
#define DH 64
#define TT 8192
#define CS 16
#define CC 512   // T / chunksize

__device__ __forceinline__ float sigf(float v) {
    return 1.0f / (1.0f + __expf(-v));
}

// ---------------------------------------------------------------------------
// K0: transpose weights.  w1 (64x512) -> w1t (512x64, d-major);
//                         w2 (512x64) -> w2t (64x512, o-major)
// ---------------------------------------------------------------------------
__global__ __launch_bounds__(256) void k_transpose(
        const float* __restrict__ w1, const float* __restrict__ w2,
        float* __restrict__ w1t, float* __restrict__ w2t) {
    int i = blockIdx.x * 256 + threadIdx.x;   // 0..32767
    // w1t[d*64 + o] = w1[o*512 + d]
    int o = i & 63, d = i >> 6;
    w1t[i] = w1[o * DD + d];
    // w2t[oo*512 + o2] = w2[o2*64 + oo]
    int o2 = i & 511, oo = i >> 9;
    w2t[i] = w2[o2 * DH + oo];
}

// ---------------------------------------------------------------------------
// K1: pooled[b,d,c] = (1/(16*(c+1))) * sum_{t<16(c+1)} x[b,d,t]
// One block per (b,d) row. 256 threads.
// ---------------------------------------------------------------------------
__global__ __launch_bounds__(256) void k_pool(
        const float* __restrict__ x, float* __restrict__ pooled) {
    const int row = blockIdx.x;               // b*512 + d
    const int t = threadIdx.x;
    const float4* xr = (const float4*)(x + (size_t)row * TT);

    __shared__ float psum[2048];              // per-float4 partial sums
    __shared__ float wtot[4];

    #pragma unroll
    for (int k = 0; k < 8; k++) {
        float4 v = xr[t + k * 256];
        psum[t + k * 256] = (v.x + v.y) + (v.z + v.w);
    }
    __syncthreads();

    // chunk c = 16 floats = 4 float4 partials; thread t owns chunks 2t, 2t+1
    const float4* ps4 = (const float4*)psum;
    float4 q0 = ps4[2 * t];
    float4 q1 = ps4[2 * t + 1];
    float c0 = (q0.x + q0.y) + (q0.z + q0.w);
    float c1 = (q1.x + q1.y) + (q1.z + q1.w);

    // inclusive scan of pair-sums across 256 threads
    float ps = c0 + c1;
    float v = ps;
    int lane = t & 63;
    #pragma unroll
    for (int off = 1; off < 64; off <<= 1) {
        float n = __shfl_up(v, off, 64);
        if (lane >= off) v += n;
    }
    int wid = t >> 6;
    if (lane == 63) wtot[wid] = v;
    __syncthreads();
    float wpre = 0.0f;
    for (int w = 0; w < wid; w++) wpre += wtot[w];
    float incl = v + wpre;          // sum of chunks 0..2t+1
    float excl = incl - ps;         // sum of chunks 0..2t-1
    float s0 = excl + c0;           // inclusive through chunk 2t
    float s1 = s0 + c1;             // inclusive through chunk 2t+1
    int c = 2 * t;
    float2 outv;
    outv.x = s0 / (float)(CS * (c + 1));
    outv.y = s1 / (float)(CS * (c + 2));
    ((float2*)(pooled + (size_t)row * CC))[t] = outv;
}

// ---------------------------------------------------------------------------
// K2: fused  h = relu(w1 @ pooled + b1);  g = sigmoid(w2 @ h + b2)
// Block = (ctile of 4 chunks, b). 256 threads.
// pooled layout (B, D, C); g layout (B, D(=o2), C).
// ---------------------------------------------------------------------------
#define PSTR 516   // padded LDS stride (516 % 32 == 4 -> conflict-free, 16B-aligned)

__global__ __launch_bounds__(256) void k_segemm(
        const float* __restrict__ pooled,
        const float* __restrict__ w1t, const float* __restrict__ b1,
        const float* __restrict__ w2t, const float* __restrict__ b2,
        float* __restrict__ g) {
    const int b = blockIdx.y;
    const int c0 = blockIdx.x * 4;
    const int t = threadIdx.x;

    __shared__ float p[4 * PSTR];   // p[c][d] = p[c*PSTR + d]
    __shared__ float hs[DH * 4];    // hs[4*o + c]

    // stage pooled[b, :, c0..c0+3] transposed into LDS
    {
        const float4* src = (const float4*)(pooled + (size_t)b * DD * CC + c0);
        float4 v0 = src[(size_t)t * (CC / 4)];
        float4 v1 = src[((size_t)t + 256) * (CC / 4)];
        p[0 * PSTR + t] = v0.x; p[1 * PSTR + t] = v0.y;
        p[2 * PSTR + t] = v0.z; p[3 * PSTR + t] = v0.w;
        p[0 * PSTR + t + 256] = v1.x; p[1 * PSTR + t + 256] = v1.y;
        p[2 * PSTR + t + 256] = v1.z; p[3 * PSTR + t + 256] = v1.w;
    }
    __syncthreads();

    // GEMM1: thread t -> o = t>>2, c = t&3 ; K = 512 over d
    const int o = t >> 2, c = t & 3;
    const float4* pc = (const float4*)(p + c * PSTR);
    float a0 = 0.f, a1 = 0.f, a2 = 0.f, a3 = 0.f;
    #pragma unroll 4
    for (int d4 = 0; d4 < 128; d4++) {
        float4 pv = pc[d4];
        int d = d4 * 4;
        a0 = fmaf(w1t[(d + 0) * DH + o], pv.x, a0);
        a1 = fmaf(w1t[(d + 1) * DH + o], pv.y, a1);
        a2 = fmaf(w1t[(d + 2) * DH + o], pv.z, a2);
        a3 = fmaf(w1t[(d + 3) * DH + o], pv.w, a3);
    }
    float hv = ((a0 + a1) + (a2 + a3)) + b1[o];
    hs[t] = fmaxf(hv, 0.0f);        // hs[4o + c] since t = 4o + c
    __syncthreads();

    // GEMM2: thread t -> o2 = {t, t+256}, 4 c's each; K = 64 over o
    float g00 = 0, g01 = 0, g02 = 0, g03 = 0;
    float g10 = 0, g11 = 0, g12 = 0, g13 = 0;
    const float4* h4 = (const float4*)hs;
    #pragma unroll 8
    for (int oo = 0; oo < DH; oo++) {
        float wv0 = w2t[oo * DD + t];
        float wv1 = w2t[oo * DD + t + 256];
        float4 h = h4[oo];
        g00 = fmaf(wv0, h.x, g00); g01 = fmaf(wv0, h.y, g01);
        g02 = fmaf(wv0, h.z, g02); g03 = fmaf(wv0, h.w, g03);
        g10 = fmaf(wv1, h.x, g10); g11 = fmaf(wv1, h.y, g11);
        g12 = fmaf(wv1, h.z, g12); g13 = fmaf(wv1, h.w, g13);
    }
    float bb0 = b2[t], bb1 = b2[t + 256];
    float4 r0, r1;
    r0.x = sigf(g00 + bb0); r0.y = sigf(g01 + bb0);
    r0.z = sigf(g02 + bb0); r0.w = sigf(g03 + bb0);
    r1.x = sigf(g10 + bb1); r1.y = sigf(g11 + bb1);
    r1.z = sigf(g12 + bb1); r1.w = sigf(g13 + bb1);
    float4* gp = (float4*)(g + (size_t)b * DD * CC + c0);
    gp[(size_t)t * (CC / 4)] = r0;
    gp[((size_t)t + 256) * (CC / 4)] = r1;
}

// ---------------------------------------------------------------------------
// K3: out[b,d,t] = g[b, d, t/16] * x[b,d,t]   (streaming, float4)
// ---------------------------------------------------------------------------
__global__ __launch_bounds__(256) void k_gate(
        const float* __restrict__ x, const float* __restrict__ g,
        float* __restrict__ out) {
    size_t i = (size_t)blockIdx.x * 256 + threadIdx.x;   // float4 index
    float4 xv = ((const float4*)x)[i];
    size_t t4  = i & (TT / 4 - 1);      // float4 index within row
    size_t row = i >> 11;               // b*512 + d
    int c = (int)(t4 >> 2);             // chunk index
    float gv = g[row * CC + c];
    float4 r;
    r.x = xv.x * gv; r.y = xv.y * gv; r.z = xv.z * gv; r.w = xv.w * gv;
    ((float4*)out)[i] = r;
}

// ---------------------------------------------------------------------------
extern "C" void kernel_launch(void* const* d_in, const int* in_sizes, int n_in,
                              void* d_out, int out_size, void* d_ws, size_t ws_size,
                              hipStream_t stream) {
    const float* x  = (const float*)d_in[0];
    const float* w1 = (const float*)d_in[1];
    const float* b1 = (const float*)d_in[2];
    const float* w2 = (const float*)d_in[3];
    const float* b2 = (const float*)d_in[4];
    float* out = (float*)d_out;

    // workspace layout (bytes): pooled 8MB | g 8MB | w1t 128KB | w2t 128KB
    char* ws = (char*)d_ws;
    float* pooled = (float*)(ws);
    float* g      = (float*)(ws + (size_t)BB * DD * CC * 4);
    float* w1t    = (float*)(ws + (size_t)2 * BB * DD * CC * 4);
    float* w2t    = (float*)(ws + (size_t)2 * BB * DD * CC * 4 + DH * DD * 4);

    k_transpose<<<dim3(32768 / 256), dim3(256), 0, stream>>>(w1, w2, w1t, w2t);
    k_pool<<<dim3(BB * DD), dim3(256), 0, stream>>>(x, pooled);
    k_segemm<<<dim3(CC / 4, BB), dim3(256), 0, stream>>>(pooled, w1t, b1, w2t, b2, g);
    k_gate<<<dim3((size_t)BB * DD * TT / 4 / 256), dim3(256), 0, stream>>>(x, g, out);
}